// Round 17
// baseline (425.173 us; speedup 1.0000x reference)
//
#include <hip/hip_runtime.h>
#include <math.h>

#define NN 50000
#define NE 800000
#define INC 32
#define HIDC 64
#define OUTC 8
#define NT_TILES ((NN + 63) / 64)      // 782
#define NPAD (NT_TILES * 64)           // 50048 padded rows
#define AS 68                           // LDS stride for 64-wide tiles
#define XS 36                           // LDS stride for 32-wide x tile
#define NCH 250                         // edge chunks (level 0 blocks)
#define ECHK (NE / NCH)                 // 3200 edges per chunk
#define BKD 128                         // dsts per fine bucket
#define NBK2 ((NN + BKD - 1) / BKD)     // 391 buckets
#define EC 12                           // register-cached edges per thread

__device__ __forceinline__ float gelu_exact(float x){
    return 0.5f * x * (1.0f + erff(x * 0.70710678118654752f));
}

// register-tiled 4x4 GEMM inner loop: acc[r][c] += At[m0+r][k] * Ws[k][n0+c]
// k-step = 4 with float4 reads on BOTH operands: 8x ds_read_b128 per 64
// FMA-instr (96 LDS-pipe cyc vs 128 VALU cyc) -> VALU-bound, not LDS-bound
// (round-16 lesson: the float2/b64 version was 48 LDS cyc per 32 FMA =
// LDS-pipe 3x oversubscribed across the CU's 4 SIMDs).
template<int ST, int KK>
__device__ __forceinline__ void mm_tile(const float* __restrict__ At,
                                        const float* __restrict__ Ws,
                                        int m0, int n0, float acc[4][4])
{
    #pragma unroll
    for (int k = 0; k < KK; k += 4){
        float4 av[4];
        #pragma unroll
        for (int r = 0; r < 4; r++)
            av[r] = *(const float4*)&At[(m0+r)*ST + k];
        float4 w0 = *(const float4*)&Ws[(k+0)*HIDC + n0];
        float4 w1 = *(const float4*)&Ws[(k+1)*HIDC + n0];
        float4 w2 = *(const float4*)&Ws[(k+2)*HIDC + n0];
        float4 w3 = *(const float4*)&Ws[(k+3)*HIDC + n0];
        #pragma unroll
        for (int r = 0; r < 4; r++){
            acc[r][0] = fmaf(av[r].x, w0.x, acc[r][0]);
            acc[r][1] = fmaf(av[r].x, w0.y, acc[r][1]);
            acc[r][2] = fmaf(av[r].x, w0.z, acc[r][2]);
            acc[r][3] = fmaf(av[r].x, w0.w, acc[r][3]);
            acc[r][0] = fmaf(av[r].y, w1.x, acc[r][0]);
            acc[r][1] = fmaf(av[r].y, w1.y, acc[r][1]);
            acc[r][2] = fmaf(av[r].y, w1.z, acc[r][2]);
            acc[r][3] = fmaf(av[r].y, w1.w, acc[r][3]);
            acc[r][0] = fmaf(av[r].z, w2.x, acc[r][0]);
            acc[r][1] = fmaf(av[r].z, w2.y, acc[r][1]);
            acc[r][2] = fmaf(av[r].z, w2.z, acc[r][2]);
            acc[r][3] = fmaf(av[r].z, w2.w, acc[r][3]);
            acc[r][0] = fmaf(av[r].w, w3.x, acc[r][0]);
            acc[r][1] = fmaf(av[r].w, w3.y, acc[r][1]);
            acc[r][2] = fmaf(av[r].w, w3.z, acc[r][2]);
            acc[r][3] = fmaf(av[r].w, w3.w, acc[r][3]);
        }
    }
}

// ---- CSR build (validated rounds 12-16) ----

__global__ __launch_bounds__(512) void k_ebin(
    const int* __restrict__ src, const int* __restrict__ dst,
    int2* __restrict__ ebuf, int* __restrict__ cnts, int* __restrict__ lboff)
{
    __shared__ int cnt[512];
    __shared__ int cur[512];
    int c = blockIdx.x, tid = threadIdx.x;
    cnt[tid] = 0;
    __syncthreads();
    int e0 = c*ECHK;
    for (int i = e0 + tid; i < e0 + ECHK; i += 512)
        atomicAdd(&cnt[dst[i] >> 7], 1);
    __syncthreads();
    int v = cnt[tid];
    for (int off = 1; off < 512; off <<= 1){
        int t = (tid >= off) ? cnt[tid-off] : 0;
        __syncthreads();
        cnt[tid] += t;
        __syncthreads();
    }
    int excl = cnt[tid] - v;
    if (tid < NBK2){
        cnts[c*NBK2 + tid]  = v;
        lboff[c*NBK2 + tid] = excl;
    }
    cur[tid] = excl;
    __syncthreads();
    for (int i = e0 + tid; i < e0 + ECHK; i += 512){
        int d = dst[i], s = src[i];
        int p = atomicAdd(&cur[d >> 7], 1);
        ebuf[e0 + p] = make_int2(d, s);
    }
}

// merged launch: blocks [0,NBK2) run choff (+init); blocks [NBK2,..) run the
// encoder. Independent work -> encoder hides under the CSR critical path.
__global__ __launch_bounds__(256) void k_choff_enc(
    const int* __restrict__ cnts, int* __restrict__ choff, int* __restrict__ btot,
    const float* __restrict__ x,
    const float* __restrict__ w1, const float* __restrict__ b1,
    const float* __restrict__ w2, const float* __restrict__ b2,
    float* __restrict__ h0, float* __restrict__ h1, int* __restrict__ row_ptr)
{
    __shared__ float w1s[INC*HIDC];
    __shared__ float w2s[HIDC*HIDC];
    __shared__ float Xt[64*XS];
    __shared__ float T[64*AS];
    int tid = threadIdx.x;
    if (blockIdx.x < NBK2){
        int b = blockIdx.x;
        int* sd = (int*)w1s;                 // alias enc's LDS
        int v = (tid < NCH) ? cnts[tid*NBK2 + b] : 0;
        sd[tid] = v;
        __syncthreads();
        for (int off = 1; off < 256; off <<= 1){
            int t = (tid >= off) ? sd[tid-off] : 0;
            __syncthreads();
            sd[tid] += t;
            __syncthreads();
        }
        if (tid < NCH) choff[b*NCH + tid] = sd[tid] - v;
        if (tid == 255) btot[b] = sd[255];
        if (b == 0){
            if (tid < 64){
                h0[(size_t)NN*HIDC + tid] = 0.f;   // dummy gather rows
                h1[(size_t)NN*HIDC + tid] = 0.f;
            }
            if (tid == 64) row_ptr[NN] = NE;
        }
        return;
    }
    int tile = blockIdx.x - NBK2;
    for (int i = tid*4; i < INC*HIDC;  i += 1024)
        *(float4*)&w1s[i] = *(const float4*)&w1[i];
    for (int i = tid*4; i < HIDC*HIDC; i += 1024)
        *(float4*)&w2s[i] = *(const float4*)&w2[i];
    for (int i = tid*4; i < 64*INC; i += 1024){
        int m = i >> 5, k = i & 31;
        int row = tile*64 + m; if (row >= NN) row = NN-1;
        *(float4*)&Xt[m*XS + k] = *(const float4*)&x[(size_t)row*INC + k];
    }
    __syncthreads();
    int tx = tid & 15, ty = tid >> 4;
    int m0 = ty*4, n0 = tx*4;
    float4 b1v = *(const float4*)&b1[n0];
    float acc[4][4];
    #pragma unroll
    for (int r = 0; r < 4; r++){
        acc[r][0]=b1v.x; acc[r][1]=b1v.y; acc[r][2]=b1v.z; acc[r][3]=b1v.w;
    }
    mm_tile<XS, INC>(Xt, w1s, m0, n0, acc);
    #pragma unroll
    for (int r = 0; r < 4; r++){
        float4 o = make_float4(gelu_exact(acc[r][0]), gelu_exact(acc[r][1]),
                               gelu_exact(acc[r][2]), gelu_exact(acc[r][3]));
        *(float4*)&T[(m0+r)*AS + n0] = o;
    }
    __syncthreads();
    float4 b2v = *(const float4*)&b2[n0];
    #pragma unroll
    for (int r = 0; r < 4; r++){
        acc[r][0]=b2v.x; acc[r][1]=b2v.y; acc[r][2]=b2v.z; acc[r][3]=b2v.w;
    }
    mm_tile<AS, HIDC>(T, w2s, m0, n0, acc);
    #pragma unroll
    for (int r = 0; r < 4; r++){
        int node = tile*64 + m0 + r;
        if (node < NN)
            *(float4*)&h0[(size_t)node*HIDC + n0] =
                make_float4(acc[r][0], acc[r][1], acc[r][2], acc[r][3]);
    }
}

// level 1 (+inline bbase): block b computes its own base = sum(btot[0..b)),
// then fine histogram + scan -> row_ptr/inv_deg, then scatter into its
// private col region (single-writer; register-cached edges).
__global__ __launch_bounds__(256) void k_bsort(
    const int2* __restrict__ ebuf, const int* __restrict__ lboff,
    const int* __restrict__ choff, const int* __restrict__ btot,
    int* __restrict__ row_ptr, int* __restrict__ col,
    float* __restrict__ inv_deg)
{
    __shared__ int cum[NCH];
    __shared__ int lb[NCH];
    __shared__ int hcnt[BKD];
    __shared__ int fpos[BKD];
    __shared__ int red[256];
    int b = blockIdx.x, tid = threadIdx.x;
    int part = 0;
    for (int i = tid; i < b; i += 256) part += btot[i];
    red[tid] = part;
    if (tid < NCH){
        cum[tid] = choff[b*NCH + tid];
        lb[tid]  = lboff[tid*NBK2 + b];
    }
    if (tid < BKD) hcnt[tid] = 0;
    __syncthreads();
    for (int off = 128; off > 0; off >>= 1){
        if (tid < off) red[tid] += red[tid + off];
        __syncthreads();
    }
    int base = red[0];
    int tot = btot[b];
    int lo = b << 7;
    int dl[EC], sv[EC];
    #pragma unroll
    for (int j = 0; j < EC; j++){
        int e = tid + j*256;
        dl[j] = -1; sv[j] = 0;
        if (e < tot){
            int lc = 0, hc = NCH;
            while (hc - lc > 1){ int mid = (lc+hc) >> 1; if (cum[mid] <= e) lc = mid; else hc = mid; }
            int2 pr = ebuf[lc*ECHK + lb[lc] + (e - cum[lc])];
            dl[j] = pr.x - lo; sv[j] = pr.y;
            atomicAdd(&hcnt[dl[j]], 1);
        }
    }
    for (int e = tid + EC*256; e < tot; e += 256){       // rare overflow
        int lc = 0, hc = NCH;
        while (hc - lc > 1){ int mid = (lc+hc) >> 1; if (cum[mid] <= e) lc = mid; else hc = mid; }
        int2 pr = ebuf[lc*ECHK + lb[lc] + (e - cum[lc])];
        atomicAdd(&hcnt[pr.x - lo], 1);
    }
    __syncthreads();
    int v = (tid < BKD) ? hcnt[tid] : 0;
    for (int off = 1; off < BKD; off <<= 1){
        int t = (tid >= off && tid < BKD) ? hcnt[tid-off] : 0;
        __syncthreads();
        if (tid < BKD) hcnt[tid] += t;
        __syncthreads();
    }
    if (tid < BKD){
        int excl = hcnt[tid] - v;
        int g = lo + tid;
        if (g < NN){
            row_ptr[g] = base + excl;
            inv_deg[g] = 1.0f / (float)max(v, 1);
        }
        fpos[tid] = base + excl;
    }
    __syncthreads();
    #pragma unroll
    for (int j = 0; j < EC; j++){
        if (dl[j] >= 0){
            int q = atomicAdd(&fpos[dl[j]], 1);
            col[q] = sv[j];
        }
    }
    for (int e = tid + EC*256; e < tot; e += 256){       // rare overflow
        int lc = 0, hc = NCH;
        while (hc - lc > 1){ int mid = (lc+hc) >> 1; if (cum[mid] <= e) lc = mid; else hc = mid; }
        int2 pr = ebuf[lc*ECHK + lb[lc] + (e - cum[lc])];
        int q = atomicAdd(&fpos[pr.x - lo], 1);
        col[q] = pr.y;
    }
}

// gather-mean: one wave per node (lane = feature); x2 unrolled loads
__global__ __launch_bounds__(256) void k_agg(
    const float* __restrict__ h_in,
    const int* __restrict__ row_ptr, const int* __restrict__ col,
    const float* __restrict__ inv_deg,
    float* __restrict__ agg)
{
    int tid = threadIdx.x;
    int wv = tid >> 6, f = tid & 63;
    int g = f >> 4, qoff = (f & 15) * 4;
    for (int node = blockIdx.x*4 + wv; node < NN; node += gridDim.x*4){
        int s0 = row_ptr[node], s1 = row_ptr[node+1];
        float a0 = 0.f, a1 = 0.f, a2 = 0.f, a3 = 0.f;
        float b0 = 0.f, b1 = 0.f, b2 = 0.f, b3 = 0.f;
        for (int p0 = s0; p0 < s1; p0 += 64){
            int cnt = s1 - p0; if (cnt > 64) cnt = 64;
            int cidx = (f < cnt) ? col[p0 + f] : NN;   // NN -> zero row
            int nq = (cnt + 3) >> 2;
            int t = 0;
            for (; t + 2 <= nq; t += 2){
                int si0 = __shfl(cidx, (t+0)*4 + g);
                int si1 = __shfl(cidx, (t+1)*4 + g);
                float4 v0 = *(const float4*)&h_in[(size_t)si0*HIDC + qoff];
                float4 v1 = *(const float4*)&h_in[(size_t)si1*HIDC + qoff];
                a0 += v0.x; a1 += v0.y; a2 += v0.z; a3 += v0.w;
                b0 += v1.x; b1 += v1.y; b2 += v1.z; b3 += v1.w;
            }
            if (t < nq){
                int si0 = __shfl(cidx, t*4 + g);
                float4 v0 = *(const float4*)&h_in[(size_t)si0*HIDC + qoff];
                a0 += v0.x; a1 += v0.y; a2 += v0.z; a3 += v0.w;
            }
        }
        a0 += b0; a1 += b1; a2 += b2; a3 += b3;
        a0 += __shfl_xor(a0, 16); a0 += __shfl_xor(a0, 32);
        a1 += __shfl_xor(a1, 16); a1 += __shfl_xor(a1, 32);
        a2 += __shfl_xor(a2, 16); a2 += __shfl_xor(a2, 32);
        a3 += __shfl_xor(a3, 16); a3 += __shfl_xor(a3, 32);
        if (g == 0){
            float idg = inv_deg[node];
            float4 o = make_float4(a0*idg, a1*idg, a2*idg, a3*idg);
            *(float4*)&agg[(size_t)node*HIDC + qoff] = o;
        }
    }
}

// ---- register-tiled LDS GEMM kernels ----

__global__ __launch_bounds__(256) void k_sage(
    const float* __restrict__ h_in, const float* __restrict__ agg,
    const float* __restrict__ wl, const float* __restrict__ wr,
    const float* __restrict__ bias, float* __restrict__ h_out)
{
    __shared__ float Wl[HIDC*HIDC];
    __shared__ float Wr[HIDC*HIDC];
    __shared__ float At[64*AS];
    int tid = threadIdx.x, tile = blockIdx.x;
    for (int i = tid*4; i < HIDC*HIDC; i += 1024){
        *(float4*)&Wl[i] = *(const float4*)&wl[i];
        *(float4*)&Wr[i] = *(const float4*)&wr[i];
    }
    const float* abase = agg + (size_t)tile*64*HIDC;
    for (int i = tid*4; i < 64*HIDC; i += 1024){
        int m = i >> 6, k = i & 63;
        *(float4*)&At[m*AS + k] = *(const float4*)&abase[i];
    }
    __syncthreads();
    int tx = tid & 15, ty = tid >> 4;
    int m0 = ty*4, n0 = tx*4;
    float4 bv = *(const float4*)&bias[n0];
    float acc[4][4];
    #pragma unroll
    for (int r = 0; r < 4; r++){
        acc[r][0]=bv.x; acc[r][1]=bv.y; acc[r][2]=bv.z; acc[r][3]=bv.w;
    }
    mm_tile<AS, HIDC>(At, Wl, m0, n0, acc);
    __syncthreads();
    const float* hbase = h_in + (size_t)tile*64*HIDC;
    for (int i = tid*4; i < 64*HIDC; i += 1024){
        int m = i >> 6, k = i & 63;
        *(float4*)&At[m*AS + k] = *(const float4*)&hbase[i];
    }
    __syncthreads();
    mm_tile<AS, HIDC>(At, Wr, m0, n0, acc);
    #pragma unroll
    for (int r = 0; r < 4; r++){
        int node = tile*64 + m0 + r;
        if (node < NN)
            *(float4*)&h_out[(size_t)node*HIDC + n0] =
                make_float4(gelu_exact(acc[r][0]), gelu_exact(acc[r][1]),
                            gelu_exact(acc[r][2]), gelu_exact(acc[r][3]));
    }
}

__global__ __launch_bounds__(256) void k_dec(
    const float* __restrict__ hbuf,
    const float* __restrict__ w1, const float* __restrict__ b1,
    const float* __restrict__ w2, const float* __restrict__ b2,
    float* __restrict__ out)
{
    __shared__ float w1s[HIDC*HIDC];
    __shared__ float w2s[HIDC*OUTC];
    __shared__ float At[64*AS];
    __shared__ float T[64*AS];
    int tid = threadIdx.x, tile = blockIdx.x;
    for (int i = tid*4; i < HIDC*HIDC; i += 1024)
        *(float4*)&w1s[i] = *(const float4*)&w1[i];
    if (tid*4 < HIDC*OUTC)
        *(float4*)&w2s[tid*4] = *(const float4*)&w2[tid*4];
    const float* hbase = hbuf + (size_t)tile*64*HIDC;
    for (int i = tid*4; i < 64*HIDC; i += 1024){
        int m = i >> 6, k = i & 63;
        *(float4*)&At[m*AS + k] = *(const float4*)&hbase[i];
    }
    __syncthreads();
    int tx = tid & 15, ty = tid >> 4;
    int m0 = ty*4, n0 = tx*4;
    float4 b1v = *(const float4*)&b1[n0];
    float acc[4][4];
    #pragma unroll
    for (int r = 0; r < 4; r++){
        acc[r][0]=b1v.x; acc[r][1]=b1v.y; acc[r][2]=b1v.z; acc[r][3]=b1v.w;
    }
    mm_tile<AS, HIDC>(At, w1s, m0, n0, acc);
    #pragma unroll
    for (int r = 0; r < 4; r++){
        float4 o = make_float4(gelu_exact(acc[r][0]), gelu_exact(acc[r][1]),
                               gelu_exact(acc[r][2]), gelu_exact(acc[r][3]));
        *(float4*)&T[(m0+r)*AS + n0] = o;
    }
    __syncthreads();
    int m = tid >> 2, c0 = (tid & 3) * 2;
    float a0 = b2[c0], a1 = b2[c0+1];
    #pragma unroll 4
    for (int k = 0; k < HIDC; k++){
        float tv = T[m*AS + k];
        float2 wv = *(const float2*)&w2s[k*OUTC + c0];
        a0 = fmaf(tv, wv.x, a0);
        a1 = fmaf(tv, wv.y, a1);
    }
    int node = tile*64 + m;
    if (node < NN)
        *(float2*)&out[(size_t)node*OUTC + c0] = make_float2(a0, a1);
}

extern "C" void kernel_launch(void* const* d_in, const int* in_sizes, int n_in,
                              void* d_out, int out_size, void* d_ws, size_t ws_size,
                              hipStream_t stream){
    const float* x      = (const float*)d_in[0];
    const int*   ei     = (const int*)  d_in[1];
    const float* enc_w1 = (const float*)d_in[2];
    const float* enc_b1 = (const float*)d_in[3];
    const float* enc_w2 = (const float*)d_in[4];
    const float* enc_b2 = (const float*)d_in[5];
    const float* sage_wl= (const float*)d_in[6];
    const float* sage_wr= (const float*)d_in[7];
    const float* sage_b = (const float*)d_in[8];
    const float* dec_w1 = (const float*)d_in[9];
    const float* dec_b1 = (const float*)d_in[10];
    const float* dec_w2 = (const float*)d_in[11];
    const float* dec_b2 = (const float*)d_in[12];
    float* out = (float*)d_out;

    char* ws = (char*)d_ws;
    size_t off = 0;
    auto alloc = [&](size_t bytes)->void*{
        void* p = ws + off; off = (off + bytes + 255) & ~(size_t)255; return p;
    };
    int*   cnts     = (int*)  alloc((size_t)NCH*NBK2*4);
    int*   lboff    = (int*)  alloc((size_t)NCH*NBK2*4);
    int*   choff    = (int*)  alloc((size_t)NBK2*NCH*4);
    int*   btot     = (int*)  alloc((size_t)NBK2*4);
    int*   row_ptr  = (int*)  alloc((size_t)(NN+1)*4);
    int*   col      = (int*)  alloc((size_t)NE*4);
    float* inv_deg  = (float*)alloc((size_t)NN*4);
    float* h0       = (float*)alloc((size_t)NPAD*HIDC*4);
    float* h1       = (float*)alloc((size_t)NPAD*HIDC*4);
    float* agg      = (float*)alloc((size_t)NPAD*HIDC*4);
    int2*  ebuf     = (int2*)agg;   // disjoint lifetime: build vs layers

    const int* srcv = ei;        // edge_index row 0
    const int* dstv = ei + NE;   // edge_index row 1

    hipLaunchKernelGGL(k_ebin, dim3(NCH), dim3(512), 0, stream,
                       srcv, dstv, ebuf, cnts, lboff);
    hipLaunchKernelGGL(k_choff_enc, dim3(NBK2 + NT_TILES), dim3(256), 0, stream,
                       cnts, choff, btot,
                       x, enc_w1, enc_b1, enc_w2, enc_b2, h0, h1, row_ptr);
    hipLaunchKernelGGL(k_bsort, dim3(NBK2), dim3(256), 0, stream,
                       ebuf, lboff, choff, btot, row_ptr, col, inv_deg);

    const float* hin = h0; float* hout = h1;
    for (int l = 0; l < 3; l++){
        hipLaunchKernelGGL(k_agg, dim3(2048), dim3(256), 0, stream,
                           hin, row_ptr, col, inv_deg, agg);
        hipLaunchKernelGGL(k_sage, dim3(NT_TILES), dim3(256), 0, stream,
                           hin, agg,
                           sage_wl + (size_t)l*HIDC*HIDC,
                           sage_wr + (size_t)l*HIDC*HIDC,
                           sage_b  + (size_t)l*HIDC,
                           hout);
        float* t = (float*)hin; hin = hout; hout = t;
    }

    hipLaunchKernelGGL(k_dec, dim3(NT_TILES), dim3(256), 0, stream,
                       hin, dec_w1, dec_b1, dec_w2, dec_b2, out);
}

// Round 18
// 214.539 us; speedup vs baseline: 1.9818x; 1.9818x over previous
//
#include <hip/hip_runtime.h>
#include <math.h>

#define NN 50000
#define NE 800000
#define INC 32
#define HIDC 64
#define OUTC 8
#define NT_TILES ((NN + 63) / 64)      // 782
#define NPAD (NT_TILES * 64)           // 50048 padded rows
#define AS 68                           // LDS stride for 64-wide tiles
#define XS 36                           // LDS stride for 32-wide x tile
#define NCH 250                         // edge chunks (level 0 blocks)
#define ECHK (NE / NCH)                 // 3200 edges per chunk
#define BKD 128                         // dsts per fine bucket
#define NBK2 ((NN + BKD - 1) / BKD)     // 391 buckets
#define EC 12                           // register-cached edges per thread

__device__ __forceinline__ float gelu_exact(float x){
    return 0.5f * x * (1.0f + erff(x * 0.70710678118654752f));
}

// register-tiled 4x4 GEMM inner loop: acc[r][c] += At[m0+r][k] * Ws[k][n0+c]
// k-step = 4 with float4 (b128) reads on BOTH operands, but LIMITED unroll:
// round-17 lesson: full unroll of 16 k-steps kept ~32 float4 temporaries
// live -> VGPR 256 + 43MB scratch spill. unroll 2 keeps live set ~100 VGPR
// while still issuing 8x ds_read_b128 per 64 FMA (96 LDS cyc : 128 VALU cyc).
template<int ST, int KK>
__device__ __forceinline__ void mm_tile(const float* __restrict__ At,
                                        const float* __restrict__ Ws,
                                        int m0, int n0, float acc[4][4])
{
    #pragma unroll 2
    for (int k = 0; k < KK; k += 4){
        float4 av[4];
        #pragma unroll
        for (int r = 0; r < 4; r++)
            av[r] = *(const float4*)&At[(m0+r)*ST + k];
        float4 w0 = *(const float4*)&Ws[(k+0)*HIDC + n0];
        float4 w1 = *(const float4*)&Ws[(k+1)*HIDC + n0];
        float4 w2 = *(const float4*)&Ws[(k+2)*HIDC + n0];
        float4 w3 = *(const float4*)&Ws[(k+3)*HIDC + n0];
        #pragma unroll
        for (int r = 0; r < 4; r++){
            acc[r][0] = fmaf(av[r].x, w0.x, acc[r][0]);
            acc[r][1] = fmaf(av[r].x, w0.y, acc[r][1]);
            acc[r][2] = fmaf(av[r].x, w0.z, acc[r][2]);
            acc[r][3] = fmaf(av[r].x, w0.w, acc[r][3]);
            acc[r][0] = fmaf(av[r].y, w1.x, acc[r][0]);
            acc[r][1] = fmaf(av[r].y, w1.y, acc[r][1]);
            acc[r][2] = fmaf(av[r].y, w1.z, acc[r][2]);
            acc[r][3] = fmaf(av[r].y, w1.w, acc[r][3]);
            acc[r][0] = fmaf(av[r].z, w2.x, acc[r][0]);
            acc[r][1] = fmaf(av[r].z, w2.y, acc[r][1]);
            acc[r][2] = fmaf(av[r].z, w2.z, acc[r][2]);
            acc[r][3] = fmaf(av[r].z, w2.w, acc[r][3]);
            acc[r][0] = fmaf(av[r].w, w3.x, acc[r][0]);
            acc[r][1] = fmaf(av[r].w, w3.y, acc[r][1]);
            acc[r][2] = fmaf(av[r].w, w3.z, acc[r][2]);
            acc[r][3] = fmaf(av[r].w, w3.w, acc[r][3]);
        }
    }
}

// ---- CSR build (validated rounds 12-16) ----

__global__ __launch_bounds__(512) void k_ebin(
    const int* __restrict__ src, const int* __restrict__ dst,
    int2* __restrict__ ebuf, int* __restrict__ cnts, int* __restrict__ lboff)
{
    __shared__ int cnt[512];
    __shared__ int cur[512];
    int c = blockIdx.x, tid = threadIdx.x;
    cnt[tid] = 0;
    __syncthreads();
    int e0 = c*ECHK;
    for (int i = e0 + tid; i < e0 + ECHK; i += 512)
        atomicAdd(&cnt[dst[i] >> 7], 1);
    __syncthreads();
    int v = cnt[tid];
    for (int off = 1; off < 512; off <<= 1){
        int t = (tid >= off) ? cnt[tid-off] : 0;
        __syncthreads();
        cnt[tid] += t;
        __syncthreads();
    }
    int excl = cnt[tid] - v;
    if (tid < NBK2){
        cnts[c*NBK2 + tid]  = v;
        lboff[c*NBK2 + tid] = excl;
    }
    cur[tid] = excl;
    __syncthreads();
    for (int i = e0 + tid; i < e0 + ECHK; i += 512){
        int d = dst[i], s = src[i];
        int p = atomicAdd(&cur[d >> 7], 1);
        ebuf[e0 + p] = make_int2(d, s);
    }
}

// merged launch: blocks [0,NBK2) run choff (+init); blocks [NBK2,..) run the
// encoder. Independent work -> encoder hides under the CSR critical path.
__global__ __launch_bounds__(256) void k_choff_enc(
    const int* __restrict__ cnts, int* __restrict__ choff, int* __restrict__ btot,
    const float* __restrict__ x,
    const float* __restrict__ w1, const float* __restrict__ b1,
    const float* __restrict__ w2, const float* __restrict__ b2,
    float* __restrict__ h0, float* __restrict__ h1, int* __restrict__ row_ptr)
{
    __shared__ float w1s[INC*HIDC];
    __shared__ float w2s[HIDC*HIDC];
    __shared__ float Xt[64*XS];
    __shared__ float T[64*AS];
    int tid = threadIdx.x;
    if (blockIdx.x < NBK2){
        int b = blockIdx.x;
        int* sd = (int*)w1s;                 // alias enc's LDS
        int v = (tid < NCH) ? cnts[tid*NBK2 + b] : 0;
        sd[tid] = v;
        __syncthreads();
        for (int off = 1; off < 256; off <<= 1){
            int t = (tid >= off) ? sd[tid-off] : 0;
            __syncthreads();
            sd[tid] += t;
            __syncthreads();
        }
        if (tid < NCH) choff[b*NCH + tid] = sd[tid] - v;
        if (tid == 255) btot[b] = sd[255];
        if (b == 0){
            if (tid < 64){
                h0[(size_t)NN*HIDC + tid] = 0.f;   // dummy gather rows
                h1[(size_t)NN*HIDC + tid] = 0.f;
            }
            if (tid == 64) row_ptr[NN] = NE;
        }
        return;
    }
    int tile = blockIdx.x - NBK2;
    for (int i = tid*4; i < INC*HIDC;  i += 1024)
        *(float4*)&w1s[i] = *(const float4*)&w1[i];
    for (int i = tid*4; i < HIDC*HIDC; i += 1024)
        *(float4*)&w2s[i] = *(const float4*)&w2[i];
    for (int i = tid*4; i < 64*INC; i += 1024){
        int m = i >> 5, k = i & 31;
        int row = tile*64 + m; if (row >= NN) row = NN-1;
        *(float4*)&Xt[m*XS + k] = *(const float4*)&x[(size_t)row*INC + k];
    }
    __syncthreads();
    int tx = tid & 15, ty = tid >> 4;
    int m0 = ty*4, n0 = tx*4;
    float4 b1v = *(const float4*)&b1[n0];
    float acc[4][4];
    #pragma unroll
    for (int r = 0; r < 4; r++){
        acc[r][0]=b1v.x; acc[r][1]=b1v.y; acc[r][2]=b1v.z; acc[r][3]=b1v.w;
    }
    mm_tile<XS, INC>(Xt, w1s, m0, n0, acc);
    #pragma unroll
    for (int r = 0; r < 4; r++){
        float4 o = make_float4(gelu_exact(acc[r][0]), gelu_exact(acc[r][1]),
                               gelu_exact(acc[r][2]), gelu_exact(acc[r][3]));
        *(float4*)&T[(m0+r)*AS + n0] = o;
    }
    __syncthreads();
    float4 b2v = *(const float4*)&b2[n0];
    #pragma unroll
    for (int r = 0; r < 4; r++){
        acc[r][0]=b2v.x; acc[r][1]=b2v.y; acc[r][2]=b2v.z; acc[r][3]=b2v.w;
    }
    mm_tile<AS, HIDC>(T, w2s, m0, n0, acc);
    #pragma unroll
    for (int r = 0; r < 4; r++){
        int node = tile*64 + m0 + r;
        if (node < NN)
            *(float4*)&h0[(size_t)node*HIDC + n0] =
                make_float4(acc[r][0], acc[r][1], acc[r][2], acc[r][3]);
    }
}

// level 1 (+inline bbase): block b computes its own base = sum(btot[0..b)),
// then fine histogram + scan -> row_ptr/inv_deg, then scatter into its
// private col region (single-writer; register-cached edges).
__global__ __launch_bounds__(256) void k_bsort(
    const int2* __restrict__ ebuf, const int* __restrict__ lboff,
    const int* __restrict__ choff, const int* __restrict__ btot,
    int* __restrict__ row_ptr, int* __restrict__ col,
    float* __restrict__ inv_deg)
{
    __shared__ int cum[NCH];
    __shared__ int lb[NCH];
    __shared__ int hcnt[BKD];
    __shared__ int fpos[BKD];
    __shared__ int red[256];
    int b = blockIdx.x, tid = threadIdx.x;
    int part = 0;
    for (int i = tid; i < b; i += 256) part += btot[i];
    red[tid] = part;
    if (tid < NCH){
        cum[tid] = choff[b*NCH + tid];
        lb[tid]  = lboff[tid*NBK2 + b];
    }
    if (tid < BKD) hcnt[tid] = 0;
    __syncthreads();
    for (int off = 128; off > 0; off >>= 1){
        if (tid < off) red[tid] += red[tid + off];
        __syncthreads();
    }
    int base = red[0];
    int tot = btot[b];
    int lo = b << 7;
    int dl[EC], sv[EC];
    #pragma unroll
    for (int j = 0; j < EC; j++){
        int e = tid + j*256;
        dl[j] = -1; sv[j] = 0;
        if (e < tot){
            int lc = 0, hc = NCH;
            while (hc - lc > 1){ int mid = (lc+hc) >> 1; if (cum[mid] <= e) lc = mid; else hc = mid; }
            int2 pr = ebuf[lc*ECHK + lb[lc] + (e - cum[lc])];
            dl[j] = pr.x - lo; sv[j] = pr.y;
            atomicAdd(&hcnt[dl[j]], 1);
        }
    }
    for (int e = tid + EC*256; e < tot; e += 256){       // rare overflow
        int lc = 0, hc = NCH;
        while (hc - lc > 1){ int mid = (lc+hc) >> 1; if (cum[mid] <= e) lc = mid; else hc = mid; }
        int2 pr = ebuf[lc*ECHK + lb[lc] + (e - cum[lc])];
        atomicAdd(&hcnt[pr.x - lo], 1);
    }
    __syncthreads();
    int v = (tid < BKD) ? hcnt[tid] : 0;
    for (int off = 1; off < BKD; off <<= 1){
        int t = (tid >= off && tid < BKD) ? hcnt[tid-off] : 0;
        __syncthreads();
        if (tid < BKD) hcnt[tid] += t;
        __syncthreads();
    }
    if (tid < BKD){
        int excl = hcnt[tid] - v;
        int g = lo + tid;
        if (g < NN){
            row_ptr[g] = base + excl;
            inv_deg[g] = 1.0f / (float)max(v, 1);
        }
        fpos[tid] = base + excl;
    }
    __syncthreads();
    #pragma unroll
    for (int j = 0; j < EC; j++){
        if (dl[j] >= 0){
            int q = atomicAdd(&fpos[dl[j]], 1);
            col[q] = sv[j];
        }
    }
    for (int e = tid + EC*256; e < tot; e += 256){       // rare overflow
        int lc = 0, hc = NCH;
        while (hc - lc > 1){ int mid = (lc+hc) >> 1; if (cum[mid] <= e) lc = mid; else hc = mid; }
        int2 pr = ebuf[lc*ECHK + lb[lc] + (e - cum[lc])];
        int q = atomicAdd(&fpos[pr.x - lo], 1);
        col[q] = pr.y;
    }
}

// gather-mean: one wave per node (lane = feature); x2 unrolled loads
__global__ __launch_bounds__(256) void k_agg(
    const float* __restrict__ h_in,
    const int* __restrict__ row_ptr, const int* __restrict__ col,
    const float* __restrict__ inv_deg,
    float* __restrict__ agg)
{
    int tid = threadIdx.x;
    int wv = tid >> 6, f = tid & 63;
    int g = f >> 4, qoff = (f & 15) * 4;
    for (int node = blockIdx.x*4 + wv; node < NN; node += gridDim.x*4){
        int s0 = row_ptr[node], s1 = row_ptr[node+1];
        float a0 = 0.f, a1 = 0.f, a2 = 0.f, a3 = 0.f;
        float b0 = 0.f, b1 = 0.f, b2 = 0.f, b3 = 0.f;
        for (int p0 = s0; p0 < s1; p0 += 64){
            int cnt = s1 - p0; if (cnt > 64) cnt = 64;
            int cidx = (f < cnt) ? col[p0 + f] : NN;   // NN -> zero row
            int nq = (cnt + 3) >> 2;
            int t = 0;
            for (; t + 2 <= nq; t += 2){
                int si0 = __shfl(cidx, (t+0)*4 + g);
                int si1 = __shfl(cidx, (t+1)*4 + g);
                float4 v0 = *(const float4*)&h_in[(size_t)si0*HIDC + qoff];
                float4 v1 = *(const float4*)&h_in[(size_t)si1*HIDC + qoff];
                a0 += v0.x; a1 += v0.y; a2 += v0.z; a3 += v0.w;
                b0 += v1.x; b1 += v1.y; b2 += v1.z; b3 += v1.w;
            }
            if (t < nq){
                int si0 = __shfl(cidx, t*4 + g);
                float4 v0 = *(const float4*)&h_in[(size_t)si0*HIDC + qoff];
                a0 += v0.x; a1 += v0.y; a2 += v0.z; a3 += v0.w;
            }
        }
        a0 += b0; a1 += b1; a2 += b2; a3 += b3;
        a0 += __shfl_xor(a0, 16); a0 += __shfl_xor(a0, 32);
        a1 += __shfl_xor(a1, 16); a1 += __shfl_xor(a1, 32);
        a2 += __shfl_xor(a2, 16); a2 += __shfl_xor(a2, 32);
        a3 += __shfl_xor(a3, 16); a3 += __shfl_xor(a3, 32);
        if (g == 0){
            float idg = inv_deg[node];
            float4 o = make_float4(a0*idg, a1*idg, a2*idg, a3*idg);
            *(float4*)&agg[(size_t)node*HIDC + qoff] = o;
        }
    }
}

// ---- register-tiled LDS GEMM kernels ----

__global__ __launch_bounds__(256) void k_sage(
    const float* __restrict__ h_in, const float* __restrict__ agg,
    const float* __restrict__ wl, const float* __restrict__ wr,
    const float* __restrict__ bias, float* __restrict__ h_out)
{
    __shared__ float Wl[HIDC*HIDC];
    __shared__ float Wr[HIDC*HIDC];
    __shared__ float At[64*AS];
    int tid = threadIdx.x, tile = blockIdx.x;
    for (int i = tid*4; i < HIDC*HIDC; i += 1024){
        *(float4*)&Wl[i] = *(const float4*)&wl[i];
        *(float4*)&Wr[i] = *(const float4*)&wr[i];
    }
    const float* abase = agg + (size_t)tile*64*HIDC;
    for (int i = tid*4; i < 64*HIDC; i += 1024){
        int m = i >> 6, k = i & 63;
        *(float4*)&At[m*AS + k] = *(const float4*)&abase[i];
    }
    __syncthreads();
    int tx = tid & 15, ty = tid >> 4;
    int m0 = ty*4, n0 = tx*4;
    float4 bv = *(const float4*)&bias[n0];
    float acc[4][4];
    #pragma unroll
    for (int r = 0; r < 4; r++){
        acc[r][0]=bv.x; acc[r][1]=bv.y; acc[r][2]=bv.z; acc[r][3]=bv.w;
    }
    mm_tile<AS, HIDC>(At, Wl, m0, n0, acc);
    __syncthreads();
    const float* hbase = h_in + (size_t)tile*64*HIDC;
    for (int i = tid*4; i < 64*HIDC; i += 1024){
        int m = i >> 6, k = i & 63;
        *(float4*)&At[m*AS + k] = *(const float4*)&hbase[i];
    }
    __syncthreads();
    mm_tile<AS, HIDC>(At, Wr, m0, n0, acc);
    #pragma unroll
    for (int r = 0; r < 4; r++){
        int node = tile*64 + m0 + r;
        if (node < NN)
            *(float4*)&h_out[(size_t)node*HIDC + n0] =
                make_float4(gelu_exact(acc[r][0]), gelu_exact(acc[r][1]),
                            gelu_exact(acc[r][2]), gelu_exact(acc[r][3]));
    }
}

__global__ __launch_bounds__(256) void k_dec(
    const float* __restrict__ hbuf,
    const float* __restrict__ w1, const float* __restrict__ b1,
    const float* __restrict__ w2, const float* __restrict__ b2,
    float* __restrict__ out)
{
    __shared__ float w1s[HIDC*HIDC];
    __shared__ float w2s[HIDC*OUTC];
    __shared__ float At[64*AS];
    __shared__ float T[64*AS];
    int tid = threadIdx.x, tile = blockIdx.x;
    for (int i = tid*4; i < HIDC*HIDC; i += 1024)
        *(float4*)&w1s[i] = *(const float4*)&w1[i];
    if (tid*4 < HIDC*OUTC)
        *(float4*)&w2s[tid*4] = *(const float4*)&w2[tid*4];
    const float* hbase = hbuf + (size_t)tile*64*HIDC;
    for (int i = tid*4; i < 64*HIDC; i += 1024){
        int m = i >> 6, k = i & 63;
        *(float4*)&At[m*AS + k] = *(const float4*)&hbase[i];
    }
    __syncthreads();
    int tx = tid & 15, ty = tid >> 4;
    int m0 = ty*4, n0 = tx*4;
    float4 b1v = *(const float4*)&b1[n0];
    float acc[4][4];
    #pragma unroll
    for (int r = 0; r < 4; r++){
        acc[r][0]=b1v.x; acc[r][1]=b1v.y; acc[r][2]=b1v.z; acc[r][3]=b1v.w;
    }
    mm_tile<AS, HIDC>(At, w1s, m0, n0, acc);
    #pragma unroll
    for (int r = 0; r < 4; r++){
        float4 o = make_float4(gelu_exact(acc[r][0]), gelu_exact(acc[r][1]),
                               gelu_exact(acc[r][2]), gelu_exact(acc[r][3]));
        *(float4*)&T[(m0+r)*AS + n0] = o;
    }
    __syncthreads();
    int m = tid >> 2, c0 = (tid & 3) * 2;
    float a0 = b2[c0], a1 = b2[c0+1];
    #pragma unroll 4
    for (int k = 0; k < HIDC; k++){
        float tv = T[m*AS + k];
        float2 wv = *(const float2*)&w2s[k*OUTC + c0];
        a0 = fmaf(tv, wv.x, a0);
        a1 = fmaf(tv, wv.y, a1);
    }
    int node = tile*64 + m;
    if (node < NN)
        *(float2*)&out[(size_t)node*OUTC + c0] = make_float2(a0, a1);
}

extern "C" void kernel_launch(void* const* d_in, const int* in_sizes, int n_in,
                              void* d_out, int out_size, void* d_ws, size_t ws_size,
                              hipStream_t stream){
    const float* x      = (const float*)d_in[0];
    const int*   ei     = (const int*)  d_in[1];
    const float* enc_w1 = (const float*)d_in[2];
    const float* enc_b1 = (const float*)d_in[3];
    const float* enc_w2 = (const float*)d_in[4];
    const float* enc_b2 = (const float*)d_in[5];
    const float* sage_wl= (const float*)d_in[6];
    const float* sage_wr= (const float*)d_in[7];
    const float* sage_b = (const float*)d_in[8];
    const float* dec_w1 = (const float*)d_in[9];
    const float* dec_b1 = (const float*)d_in[10];
    const float* dec_w2 = (const float*)d_in[11];
    const float* dec_b2 = (const float*)d_in[12];
    float* out = (float*)d_out;

    char* ws = (char*)d_ws;
    size_t off = 0;
    auto alloc = [&](size_t bytes)->void*{
        void* p = ws + off; off = (off + bytes + 255) & ~(size_t)255; return p;
    };
    int*   cnts     = (int*)  alloc((size_t)NCH*NBK2*4);
    int*   lboff    = (int*)  alloc((size_t)NCH*NBK2*4);
    int*   choff    = (int*)  alloc((size_t)NBK2*NCH*4);
    int*   btot     = (int*)  alloc((size_t)NBK2*4);
    int*   row_ptr  = (int*)  alloc((size_t)(NN+1)*4);
    int*   col      = (int*)  alloc((size_t)NE*4);
    float* inv_deg  = (float*)alloc((size_t)NN*4);
    float* h0       = (float*)alloc((size_t)NPAD*HIDC*4);
    float* h1       = (float*)alloc((size_t)NPAD*HIDC*4);
    float* agg      = (float*)alloc((size_t)NPAD*HIDC*4);
    int2*  ebuf     = (int2*)agg;   // disjoint lifetime: build vs layers

    const int* srcv = ei;        // edge_index row 0
    const int* dstv = ei + NE;   // edge_index row 1

    hipLaunchKernelGGL(k_ebin, dim3(NCH), dim3(512), 0, stream,
                       srcv, dstv, ebuf, cnts, lboff);
    hipLaunchKernelGGL(k_choff_enc, dim3(NBK2 + NT_TILES), dim3(256), 0, stream,
                       cnts, choff, btot,
                       x, enc_w1, enc_b1, enc_w2, enc_b2, h0, h1, row_ptr);
    hipLaunchKernelGGL(k_bsort, dim3(NBK2), dim3(256), 0, stream,
                       ebuf, lboff, choff, btot, row_ptr, col, inv_deg);

    const float* hin = h0; float* hout = h1;
    for (int l = 0; l < 3; l++){
        hipLaunchKernelGGL(k_agg, dim3(2048), dim3(256), 0, stream,
                           hin, row_ptr, col, inv_deg, agg);
        hipLaunchKernelGGL(k_sage, dim3(NT_TILES), dim3(256), 0, stream,
                           hin, agg,
                           sage_wl + (size_t)l*HIDC*HIDC,
                           sage_wr + (size_t)l*HIDC*HIDC,
                           sage_b  + (size_t)l*HIDC,
                           hout);
        float* t = (float*)hin; hin = hout; hout = t;
    }

    hipLaunchKernelGGL(k_dec, dim3(NT_TILES), dim3(256), 0, stream,
                       hin, dec_w1, dec_b1, dec_w2, dec_b2, out);
}